// Round 1
// baseline (215.702 us; speedup 1.0000x reference)
//
#include <hip/hip_runtime.h>
#include <hip/hip_bf16.h>
#include <stdint.h>

typedef short short8 __attribute__((ext_vector_type(8)));
typedef float f32x4  __attribute__((ext_vector_type(4)));
typedef unsigned short u16;

#define B_ROWS 4096
#define NEXP   8
#define IN_D   1024
#define OUT_D  1024

#define BM 128
#define BN 128
#define BK 64

// ---------- fp32 -> bf16 (RNE), 4 elems/thread ----------
__device__ __forceinline__ u16 f2bf(float f) {
    uint32_t u = __float_as_uint(f);
    uint32_t r = (u + 0x7fffu + ((u >> 16) & 1u)) >> 16;
    return (u16)r;
}

__global__ __launch_bounds__(256) void cvt_bf16(const float* __restrict__ in,
                                                u16* __restrict__ out, int n4) {
    int i = blockIdx.x * 256 + threadIdx.x;
    if (i >= n4) return;
    float4 v = reinterpret_cast<const float4*>(in)[i];
    ushort4 o;
    o.x = f2bf(v.x); o.y = f2bf(v.y); o.z = f2bf(v.z); o.w = f2bf(v.w);
    reinterpret_cast<ushort4*>(out)[i] = o;
}

// ---------- async global->LDS, 16B per lane ----------
__device__ __forceinline__ void glds16(const u16* g, u16* lds_base, int off_bytes) {
    auto gp = (const __attribute__((address_space(1))) void*)(uintptr_t)(g);
    auto lp = (__attribute__((address_space(3))) void*)(uintptr_t)((const char*)lds_base + off_bytes);
    __builtin_amdgcn_global_load_lds(gp, lp, 16, 0, 0);
}

// ---------- MoE GEMM: C_partial[z] = sum over experts-in-z of bw .* (x @ W_k^T) ----------
__global__ __launch_bounds__(256, 2) void moe_gemm(
    const u16* __restrict__ Xb,   // [4096][1024] bf16
    const u16* __restrict__ Wb,   // [8][1024][1024] bf16 (k,o,i)
    const float* __restrict__ bwt,// [4096][8]
    float* __restrict__ outp,     // [nz][4096][1024] fp32 partials (or d_out if nz==1)
    int epb)                      // experts per z-block
{
    __shared__ __align__(16) u16 As[BM * BK];
    __shared__ __align__(16) u16 Bs[BN * BK];

    const int tid  = threadIdx.x;
    const int lane = tid & 63, wid = tid >> 6;
    const int wm = wid >> 1, wn = wid & 1;        // 2x2 wave grid, 64x64 per wave
    const int lr = lane & 15, lg = lane >> 4;
    const int bn = blockIdx.x * BN;
    const int bm = blockIdx.y * BM;
    const int bz = blockIdx.z;

    // staging: tile = 128 rows x 64 cols bf16 = 16KB = 1024 chunks of 16B.
    // chunk c = r*256 + wid*64 + lane ; LDS dest (wave-uniform) = (r*256+wid*64)*16 + lane*16 (HW).
    int st_row[4], st_col[4], st_off[4];
    #pragma unroll
    for (int r = 0; r < 4; ++r) {
        int c = r * 256 + wid * 64 + lane;
        st_row[r] = c >> 3;          // 8 chunks per 64-col row
        st_col[r] = (c & 7) * 8;
        st_off[r] = (r * 256 + wid * 64) * 16;
    }

    f32x4 acc_t[4][4];
    #pragma unroll
    for (int mi = 0; mi < 4; ++mi)
        #pragma unroll
        for (int ni = 0; ni < 4; ++ni)
            acc_t[mi][ni] = (f32x4){0.f, 0.f, 0.f, 0.f};

    const int nsteps = IN_D / BK; // 16
    for (int e = 0; e < epb; ++e) {
        const int kexp = bz * epb + e;
        const u16* Wk = Wb + (size_t)kexp * OUT_D * IN_D;

        f32x4 acc_e[4][4];
        #pragma unroll
        for (int mi = 0; mi < 4; ++mi)
            #pragma unroll
            for (int ni = 0; ni < 4; ++ni)
                acc_e[mi][ni] = (f32x4){0.f, 0.f, 0.f, 0.f};

        for (int it = 0; it < nsteps; ++it) {
            const int i0 = it * BK;
            __syncthreads();   // previous compute done before LDS overwrite
            #pragma unroll
            for (int r = 0; r < 4; ++r) {
                glds16(Xb + (size_t)(bm + st_row[r]) * IN_D + i0 + st_col[r], As, st_off[r]);
                glds16(Wk + (size_t)(bn + st_row[r]) * IN_D + i0 + st_col[r], Bs, st_off[r]);
            }
            __syncthreads();   // compiler drains vmcnt before barrier

            #pragma unroll
            for (int ks = 0; ks < 2; ++ks) {
                short8 a[4], b[4];
                #pragma unroll
                for (int mi = 0; mi < 4; ++mi)
                    a[mi] = *(const short8*)(As + (wm * 64 + mi * 16 + lr) * BK + ks * 32 + lg * 8);
                #pragma unroll
                for (int ni = 0; ni < 4; ++ni)
                    b[ni] = *(const short8*)(Bs + (wn * 64 + ni * 16 + lr) * BK + ks * 32 + lg * 8);
                #pragma unroll
                for (int mi = 0; mi < 4; ++mi)
                    #pragma unroll
                    for (int ni = 0; ni < 4; ++ni)
                        acc_e[mi][ni] = __builtin_amdgcn_mfma_f32_16x16x32_bf16(
                            a[mi], b[ni], acc_e[mi][ni], 0, 0, 0);
            }
        }

        // blend this expert into the total: acc_t += bw[row, kexp] * acc_e
        #pragma unroll
        for (int mi = 0; mi < 4; ++mi) {
            #pragma unroll
            for (int r = 0; r < 4; ++r) {
                const int grow = bm + wm * 64 + mi * 16 + lg * 4 + r;
                const float w = bwt[grow * NEXP + kexp];
                #pragma unroll
                for (int ni = 0; ni < 4; ++ni)
                    acc_t[mi][ni][r] += w * acc_e[mi][ni][r];
            }
        }
    }

    // epilogue: C/D mapping col=lane&15, row=(lane>>4)*4+reg (m89-verified)
    float* op = outp + (size_t)bz * B_ROWS * OUT_D;
    #pragma unroll
    for (int mi = 0; mi < 4; ++mi)
        #pragma unroll
        for (int ni = 0; ni < 4; ++ni)
            #pragma unroll
            for (int r = 0; r < 4; ++r) {
                const int grow = bm + wm * 64 + mi * 16 + lg * 4 + r;
                const int gcol = bn + wn * 64 + ni * 16 + lr;
                op[(size_t)grow * OUT_D + gcol] = acc_t[mi][ni][r];
            }
}

// ---------- reduce partials + bias blend ----------
// nz>0: out = sum_z parts[z] + bw@bias ; nz==0: out += bw@bias (in-place on d_out)
__global__ __launch_bounds__(256) void reduce_bias(
    const float* __restrict__ parts, const float* __restrict__ bwt,
    const float* __restrict__ bias, float* __restrict__ out, int nz)
{
    const int i4 = blockIdx.x * 256 + threadIdx.x;
    const size_t total = (size_t)B_ROWS * OUT_D;
    const size_t base = (size_t)i4 * 4;
    if (base >= total) return;
    const int brow = (int)(base >> 10);
    const int o = (int)(base & 1023);

    float4 s;
    if (nz == 0) s = *reinterpret_cast<const float4*>(out + base);
    else         s = make_float4(0.f, 0.f, 0.f, 0.f);
    for (int z = 0; z < nz; ++z) {
        float4 p = *reinterpret_cast<const float4*>(parts + (size_t)z * total + base);
        s.x += p.x; s.y += p.y; s.z += p.z; s.w += p.w;
    }
    #pragma unroll
    for (int k = 0; k < NEXP; ++k) {
        const float w = bwt[brow * NEXP + k];
        float4 bb = *reinterpret_cast<const float4*>(bias + k * OUT_D + o);
        s.x += w * bb.x; s.y += w * bb.y; s.z += w * bb.z; s.w += w * bb.w;
    }
    *reinterpret_cast<float4*>(out + base) = s;
}

// ---------- emergency fallback (ws too small): fp32 direct ----------
__global__ __launch_bounds__(256) void naive_moe(
    const float* __restrict__ x, const float* __restrict__ bwt,
    const float* __restrict__ wgt, const float* __restrict__ bias,
    float* __restrict__ out)
{
    __shared__ float xs[IN_D];
    const int brow = blockIdx.x;
    const int o = blockIdx.y * 256 + threadIdx.x;
    for (int i = threadIdx.x; i < IN_D; i += 256) xs[i] = x[(size_t)brow * IN_D + i];
    __syncthreads();
    float acc = 0.f;
    for (int k = 0; k < NEXP; ++k) {
        const float* wr = wgt + ((size_t)k * OUT_D + o) * IN_D;
        float d = 0.f;
        for (int i = 0; i < IN_D; ++i) d += xs[i] * wr[i];
        acc += bwt[brow * NEXP + k] * (d + bias[k * OUT_D + o]);
    }
    out[(size_t)brow * OUT_D + o] = acc;
}

extern "C" void kernel_launch(void* const* d_in, const int* in_sizes, int n_in,
                              void* d_out, int out_size, void* d_ws, size_t ws_size,
                              hipStream_t stream) {
    const float* x    = (const float*)d_in[0];
    const float* bwt  = (const float*)d_in[1];
    const float* wgt  = (const float*)d_in[2];
    const float* bias = (const float*)d_in[3];
    float* out = (float*)d_out;

    const size_t xb_bytes   = (size_t)B_ROWS * IN_D * 2;        // 8 MiB
    const size_t wb_bytes   = (size_t)NEXP * OUT_D * IN_D * 2;  // 16 MiB
    const size_t part_bytes = (size_t)B_ROWS * OUT_D * 4;       // 16 MiB
    const size_t base_bytes = xb_bytes + wb_bytes;              // 24 MiB

    if (ws_size < base_bytes) {
        naive_moe<<<dim3(B_ROWS, OUT_D / 256), 256, 0, stream>>>(x, bwt, wgt, bias, out);
        return;
    }

    int nz = 1;
    if      (ws_size >= base_bytes + 4 * part_bytes) nz = 4;
    else if (ws_size >= base_bytes + 2 * part_bytes) nz = 2;
    const bool have_part = ws_size >= base_bytes + (size_t)nz * part_bytes;

    u16* xb = (u16*)d_ws;
    u16* wb = (u16*)((char*)d_ws + xb_bytes);
    float* parts = (float*)((char*)d_ws + base_bytes);

    cvt_bf16<<<(B_ROWS * IN_D / 4 + 255) / 256, 256, 0, stream>>>(x, xb, B_ROWS * IN_D / 4);
    cvt_bf16<<<(NEXP * OUT_D * IN_D / 4 + 255) / 256, 256, 0, stream>>>(wgt, wb, NEXP * OUT_D * IN_D / 4);

    float* gout = have_part ? parts : out;
    moe_gemm<<<dim3(OUT_D / BN, B_ROWS / BM, nz), 256, 0, stream>>>(xb, wb, bwt, gout, NEXP / nz);

    reduce_bias<<<((B_ROWS * OUT_D / 4) + 255) / 256, 256, 0, stream>>>(
        have_part ? parts : nullptr, bwt, bias, out, have_part ? nz : 0);
}

// Round 2
// 205.740 us; speedup vs baseline: 1.0484x; 1.0484x over previous
//
#include <hip/hip_runtime.h>
#include <hip/hip_bf16.h>
#include <stdint.h>

typedef short short8 __attribute__((ext_vector_type(8)));
typedef float f32x4  __attribute__((ext_vector_type(4)));
typedef unsigned short u16;

#define B_ROWS 4096
#define NEXP   8
#define IN_D   1024
#define OUT_D  1024

#define BM 128
#define BN 128
#define BK 64

// ---------- fp32 -> bf16 (RNE) ----------
__device__ __forceinline__ u16 f2bf(float f) {
    uint32_t u = __float_as_uint(f);
    uint32_t r = (u + 0x7fffu + ((u >> 16) & 1u)) >> 16;
    return (u16)r;
}

// ---------- build A[k][b][i] = bf16(bw[b,k] * x[b,i]) ----------
__global__ __launch_bounds__(256) void build_a(const float* __restrict__ x,
                                               const float* __restrict__ bwt,
                                               u16* __restrict__ a) {
    const int t = blockIdx.x * 256 + threadIdx.x;   // 4096*256 threads
    const int b = t >> 8, i4 = t & 255;
    float4 v = reinterpret_cast<const float4*>(x)[(size_t)b * 256 + i4];
    float4 w0 = reinterpret_cast<const float4*>(bwt)[b * 2];
    float4 w1 = reinterpret_cast<const float4*>(bwt)[b * 2 + 1];
    float wk[8] = {w0.x, w0.y, w0.z, w0.w, w1.x, w1.y, w1.z, w1.w};
    #pragma unroll
    for (int k = 0; k < NEXP; ++k) {
        ushort4 o;
        o.x = f2bf(wk[k] * v.x); o.y = f2bf(wk[k] * v.y);
        o.z = f2bf(wk[k] * v.z); o.w = f2bf(wk[k] * v.w);
        reinterpret_cast<ushort4*>(a)[((size_t)k * B_ROWS + b) * 256 + i4] = o;
    }
}

// ---------- fp32 -> bf16 straight convert (for W) ----------
__global__ __launch_bounds__(256) void cvt_bf16(const float* __restrict__ in,
                                                u16* __restrict__ out, int n4) {
    int i = blockIdx.x * 256 + threadIdx.x;
    if (i >= n4) return;
    float4 v = reinterpret_cast<const float4*>(in)[i];
    ushort4 o;
    o.x = f2bf(v.x); o.y = f2bf(v.y); o.z = f2bf(v.z); o.w = f2bf(v.w);
    reinterpret_cast<ushort4*>(out)[i] = o;
}

// ---------- async global->LDS, 16B per lane ----------
__device__ __forceinline__ void glds16(const u16* g, u16* lds_base, int off_bytes) {
    auto gp = (const __attribute__((address_space(1))) void*)(uintptr_t)(g);
    auto lp = (__attribute__((address_space(3))) void*)(uintptr_t)((const char*)lds_base + off_bytes);
    __builtin_amdgcn_global_load_lds(gp, lp, 16, 0, 0);
}

// ---------- GEMM: out_z = sum over experts in z of A_k @ W_k^T (single accumulator) ----------
__global__ __launch_bounds__(256) void moe_gemm(
    const u16* __restrict__ Ab,   // [8][4096][1024] bf16 (pre-scaled by blend weights)
    const u16* __restrict__ Wb,   // [8][1024][1024] bf16 (k,o,i)
    float* __restrict__ out0,     // z==0 target
    float* __restrict__ out1,     // z==1 target
    int epb)                      // experts per z-block
{
    __shared__ __align__(16) u16 As[BM * BK];
    __shared__ __align__(16) u16 Bs[BN * BK];

    const int tid  = threadIdx.x;
    const int lane = tid & 63, wid = tid >> 6;
    const int wm = wid >> 1, wn = wid & 1;        // 2x2 wave grid, 64x64 per wave
    const int lr = lane & 15, lg = lane >> 4;
    const int bn = blockIdx.x * BN;
    const int bm = blockIdx.y * BM;
    const int bz = blockIdx.z;

    // staging: tile = 128 rows x 64 cols bf16 = 16KB = 1024 chunks of 16B.
    int st_row[4], st_col[4], st_off[4];
    #pragma unroll
    for (int r = 0; r < 4; ++r) {
        int c = r * 256 + wid * 64 + lane;
        st_row[r] = c >> 3;
        st_col[r] = (c & 7) * 8;
        st_off[r] = (r * 256 + wid * 64) * 16;
    }

    f32x4 acc[4][4];
    #pragma unroll
    for (int mi = 0; mi < 4; ++mi)
        #pragma unroll
        for (int ni = 0; ni < 4; ++ni)
            acc[mi][ni] = (f32x4){0.f, 0.f, 0.f, 0.f};

    const int nsteps = IN_D / BK; // 16
    for (int e = 0; e < epb; ++e) {
        const int kexp = bz * epb + e;
        const u16* Ak = Ab + (size_t)kexp * B_ROWS * IN_D;
        const u16* Wk = Wb + (size_t)kexp * OUT_D * IN_D;

        for (int it = 0; it < nsteps; ++it) {
            const int i0 = it * BK;
            __syncthreads();   // previous compute done before LDS overwrite
            #pragma unroll
            for (int r = 0; r < 4; ++r) {
                glds16(Ak + (size_t)(bm + st_row[r]) * IN_D + i0 + st_col[r], As, st_off[r]);
                glds16(Wk + (size_t)(bn + st_row[r]) * IN_D + i0 + st_col[r], Bs, st_off[r]);
            }
            __syncthreads();   // compiler drains vmcnt before barrier

            #pragma unroll
            for (int ks = 0; ks < 2; ++ks) {
                short8 a[4], b[4];
                #pragma unroll
                for (int mi = 0; mi < 4; ++mi)
                    a[mi] = *(const short8*)(As + (wm * 64 + mi * 16 + lr) * BK + ks * 32 + lg * 8);
                #pragma unroll
                for (int ni = 0; ni < 4; ++ni)
                    b[ni] = *(const short8*)(Bs + (wn * 64 + ni * 16 + lr) * BK + ks * 32 + lg * 8);
                #pragma unroll
                for (int mi = 0; mi < 4; ++mi)
                    #pragma unroll
                    for (int ni = 0; ni < 4; ++ni)
                        acc[mi][ni] = __builtin_amdgcn_mfma_f32_16x16x32_bf16(
                            a[mi], b[ni], acc[mi][ni], 0, 0, 0);
            }
        }
    }

    // epilogue: C/D mapping col=lane&15, row=(lane>>4)*4+reg (m89-verified)
    float* op = (bz == 0) ? out0 : out1;
    #pragma unroll
    for (int mi = 0; mi < 4; ++mi)
        #pragma unroll
        for (int ni = 0; ni < 4; ++ni)
            #pragma unroll
            for (int r = 0; r < 4; ++r) {
                const int grow = bm + wm * 64 + mi * 16 + lg * 4 + r;
                const int gcol = bn + wn * 64 + ni * 16 + lr;
                op[(size_t)grow * OUT_D + gcol] = acc[mi][ni][r];
            }
}

// ---------- finalize: out += (np partial buffers) + bw@bias ----------
__global__ __launch_bounds__(256) void reduce_bias(
    const float* __restrict__ parts, const float* __restrict__ bwt,
    const float* __restrict__ bias, float* __restrict__ out, int np)
{
    const int i4 = blockIdx.x * 256 + threadIdx.x;
    const size_t total = (size_t)B_ROWS * OUT_D;
    const size_t base = (size_t)i4 * 4;
    if (base >= total) return;
    const int brow = (int)(base >> 10);
    const int o = (int)(base & 1023);

    float4 s = *reinterpret_cast<const float4*>(out + base);
    for (int z = 0; z < np; ++z) {
        float4 p = *reinterpret_cast<const float4*>(parts + (size_t)z * total + base);
        s.x += p.x; s.y += p.y; s.z += p.z; s.w += p.w;
    }
    #pragma unroll
    for (int k = 0; k < NEXP; ++k) {
        const float w = bwt[brow * NEXP + k];
        float4 bb = *reinterpret_cast<const float4*>(bias + k * OUT_D + o);
        s.x += w * bb.x; s.y += w * bb.y; s.z += w * bb.z; s.w += w * bb.w;
    }
    *reinterpret_cast<float4*>(out + base) = s;
}

// ---------- emergency fallback (ws too small): fp32 direct ----------
__global__ __launch_bounds__(256) void naive_moe(
    const float* __restrict__ x, const float* __restrict__ bwt,
    const float* __restrict__ wgt, const float* __restrict__ bias,
    float* __restrict__ out)
{
    __shared__ float xs[IN_D];
    const int brow = blockIdx.x;
    const int o = blockIdx.y * 256 + threadIdx.x;
    for (int i = threadIdx.x; i < IN_D; i += 256) xs[i] = x[(size_t)brow * IN_D + i];
    __syncthreads();
    float acc = 0.f;
    for (int k = 0; k < NEXP; ++k) {
        const float* wr = wgt + ((size_t)k * OUT_D + o) * IN_D;
        float d = 0.f;
        for (int i = 0; i < IN_D; ++i) d += xs[i] * wr[i];
        acc += bwt[brow * NEXP + k] * (d + bias[k * OUT_D + o]);
    }
    out[(size_t)brow * OUT_D + o] = acc;
}

extern "C" void kernel_launch(void* const* d_in, const int* in_sizes, int n_in,
                              void* d_out, int out_size, void* d_ws, size_t ws_size,
                              hipStream_t stream) {
    const float* x    = (const float*)d_in[0];
    const float* bwt  = (const float*)d_in[1];
    const float* wgt  = (const float*)d_in[2];
    const float* bias = (const float*)d_in[3];
    float* out = (float*)d_out;

    const size_t a_bytes    = (size_t)NEXP * B_ROWS * IN_D * 2;  // 64 MiB
    const size_t w_bytes    = (size_t)NEXP * OUT_D * IN_D * 2;   // 16 MiB
    const size_t part_bytes = (size_t)B_ROWS * OUT_D * 4;        // 16 MiB

    if (ws_size < a_bytes + w_bytes) {
        naive_moe<<<dim3(B_ROWS, OUT_D / 256), 256, 0, stream>>>(x, bwt, wgt, bias, out);
        return;
    }

    u16* ab = (u16*)d_ws;
    u16* wb = (u16*)((char*)d_ws + a_bytes);
    float* parts = (float*)((char*)d_ws + a_bytes + w_bytes);

    const int nz = (ws_size >= a_bytes + w_bytes + part_bytes) ? 2 : 1;

    build_a<<<B_ROWS, 256, 0, stream>>>(x, bwt, ab);
    cvt_bf16<<<(NEXP * OUT_D * IN_D / 4 + 255) / 256, 256, 0, stream>>>(
        wgt, wb, NEXP * OUT_D * IN_D / 4);

    if (nz == 2) {
        // z=0 -> partial buffer, z=1 -> d_out; finalize sums them + bias
        moe_gemm<<<dim3(OUT_D / BN, B_ROWS / BM, 2), 256, 0, stream>>>(ab, wb, parts, out, NEXP / 2);
        reduce_bias<<<((B_ROWS * OUT_D / 4) + 255) / 256, 256, 0, stream>>>(parts, bwt, bias, out, 1);
    } else {
        moe_gemm<<<dim3(OUT_D / BN, B_ROWS / BM, 1), 256, 0, stream>>>(ab, wb, out, out, NEXP);
        reduce_bias<<<((B_ROWS * OUT_D / 4) + 255) / 256, 256, 0, stream>>>(nullptr, bwt, bias, out, 0);
    }
}